// Round 1
// baseline (224.492 us; speedup 1.0000x reference)
//
#include <hip/hip_runtime.h>
#include <hip/hip_bf16.h>
#include <stdint.h>

#define Bsz 4096
#define Dn  512
#define Kn  128
#define Pn  16
#define An  32
#define TB  16

typedef __attribute__((ext_vector_type(4))) float  floatx4;
typedef __attribute__((ext_vector_type(8))) short  shortx8;

__device__ __forceinline__ unsigned short f2bf(float x) {
    union { float f; uint32_t u; } v; v.f = x;
    uint32_t u = v.u;
    uint32_t r = (u + 0x7FFFu + ((u >> 16) & 1u)) >> 16;
    return (unsigned short)r;
}

// ---------------- K1a: mu = alpha @ W, plus bf16 copy and ||mu_k||^2 ----------------
__global__ __launch_bounds__(256) void k_mu(const float* __restrict__ alpha,
                                            const float* __restrict__ W,
                                            float* __restrict__ mu_f,
                                            unsigned short* __restrict__ mu_bf,
                                            float* __restrict__ munorm) {
    __shared__ float al[An];
    __shared__ float red[4];
    int k = blockIdx.x, t = threadIdx.x;
    if (t < An) al[t] = alpha[k * An + t];
    __syncthreads();
    int d0 = t, d1 = t + 256;
    float a0 = 0.f, a1 = 0.f;
#pragma unroll
    for (int a = 0; a < An; ++a) {
        float av = al[a];
        a0 = fmaf(av, W[a * Dn + d0], a0);
        a1 = fmaf(av, W[a * Dn + d1], a1);
    }
    mu_f[k * Dn + d0] = a0;  mu_f[k * Dn + d1] = a1;
    mu_bf[k * Dn + d0] = f2bf(a0);  mu_bf[k * Dn + d1] = f2bf(a1);
    float nrm = a0 * a0 + a1 * a1;
#pragma unroll
    for (int msk = 1; msk < 64; msk <<= 1) nrm += __shfl_xor(nrm, msk);
    if ((t & 63) == 0) red[t >> 6] = nrm;
    __syncthreads();
    if (t == 0) munorm[k] = red[0] + red[1] + red[2] + red[3];
}

// ---------------- K1b: Gram G = mu @ mu^T (bf16, symmetric) ----------------
__global__ __launch_bounds__(256) void k_gram(const float* __restrict__ mu_f,
                                              unsigned short* __restrict__ G_bf) {
    __shared__ float mi[Dn];
    __shared__ float hsum[128];
    int i = blockIdx.x, t = threadIdx.x;
    mi[t] = mu_f[i * Dn + t];
    mi[t + 256] = mu_f[i * Dn + t + 256];
    __syncthreads();
    int j = t >> 1, h = t & 1;
    const float* rj = mu_f + (size_t)j * Dn + h * 256;
    const float* ri = mi + h * 256;
    float acc = 0.f;
#pragma unroll 8
    for (int d = 0; d < 256; ++d) acc = fmaf(ri[d], rj[d], acc);
    if (h) hsum[j] = acc;
    __syncthreads();
    if (!h) G_bf[i * Kn + j] = f2bf(acc + hsum[j]);
}

// ---------------- K3: fused S/softmax/wGw + streaming probe contraction ----------------
__global__ __launch_bounds__(512, 2) void k_main(
    const float* __restrict__ thetas,
    const int* __restrict__ v_int,
    const unsigned short* __restrict__ mu_bf,
    const float* __restrict__ munorm,
    const unsigned short* __restrict__ G_bf,
    const int* __restrict__ Np,
    float* __restrict__ out)
{
    __shared__ short vt[TB][520];      // staged A-tile (theta or v), bf16, +16B pad
    __shared__ float S_l[TB][132];     // S scores
    __shared__ float w_l[TB][132];     // softmax weights fp32
    __shared__ short wbf[TB][136];     // softmax weights bf16 (A-frag source)
    __shared__ float part[8][TB][2];   // per-wave epilogue partials
    __shared__ float thn[TB];
    __shared__ float SwS[TB];

    const int tid = threadIdx.x;
    const int lane = tid & 63;
    const int wv = tid >> 6;         // wave 0..7 -> k-range [wv*16, wv*16+16)
    const int m = lane & 15;
    const int q = lane >> 4;

    const int tileb = blockIdx.x >> 1;
    const int phalf = blockIdx.x & 1;
    const int b0 = tileb * TB;
    const int p0 = phalf * 8;

    const float Nf = (float)(*Np);
    const float temper = Nf / (Nf + 1.0f);

    // mu B-fragments: lane holds B[d = dc*32 + q*8 + j][n = m], k_col = wv*16+m
    const int kcol = wv * 16 + m;
    shortx8 mufrag[16];
    {
        const unsigned short* mb = mu_bf + (size_t)kcol * Dn + q * 8;
#pragma unroll
        for (int dc = 0; dc < 16; ++dc)
            mufrag[dc] = *(const shortx8*)(mb + dc * 32);
    }
    // G B-fragments (G symmetric: column kcol == row kcol -> contiguous load)
    shortx8 gfrag[4];
    {
        const unsigned short* gb = G_bf + (size_t)kcol * Kn + q * 8;
#pragma unroll
        for (int kc = 0; kc < 4; ++kc)
            gfrag[kc] = *(const shortx8*)(gb + kc * 32);
    }

    // staging geometry: thread covers 16 consecutive elements; block covers
    // a contiguous 32KB region (rows b0..b0+15) -> perfectly coalesced
    const int r = tid >> 5;
    const int c0 = (tid & 31) * 16;
    const size_t PB = (size_t)Bsz * Dn;
    const int* vrow = v_int + (size_t)(b0 + r) * Dn + c0;

    int4 buf[2][4];
    {   // prefetch probe p0 while we do the theta pass
        const int4* g = (const int4*)(vrow + (size_t)p0 * PB);
#pragma unroll
        for (int j = 0; j < 4; ++j) buf[0][j] = g[j];
    }
    {   // stage theta (fp32 -> bf16) and compute ||theta||^2 in fp32
        const float4* tg = (const float4*)(thetas + (size_t)(b0 + r) * Dn + c0);
        float tn = 0.f;
#pragma unroll
        for (int j = 0; j < 4; ++j) {
            float4 f = tg[j];
            tn += f.x * f.x + f.y * f.y + f.z * f.z + f.w * f.w;
            short4 h;
            h.x = (short)f2bf(f.x); h.y = (short)f2bf(f.y);
            h.z = (short)f2bf(f.z); h.w = (short)f2bf(f.w);
            *(short4*)&vt[r][c0 + j * 4] = h;
        }
#pragma unroll
        for (int msk = 1; msk < 32; msk <<= 1) tn += __shfl_xor(tn, msk);
        if ((tid & 31) == 0) thn[r] = tn;
    }
    __syncthreads();

    // ---- S pass: S = theta @ mu^T ----
    {
        floatx4 acc = {0.f, 0.f, 0.f, 0.f};
#pragma unroll
        for (int dc = 0; dc < 16; ++dc) {
            shortx8 a = *(const shortx8*)&vt[m][dc * 32 + q * 8];
            acc = __builtin_amdgcn_mfma_f32_16x16x32_bf16(a, mufrag[dc], acc, 0, 0, 0);
        }
#pragma unroll
        for (int i = 0; i < 4; ++i) S_l[q * 4 + i][kcol] = acc[i];
    }
    __syncthreads();

    // ---- softmax over k per b (32 threads per b) ----
    {
        const int b = tid >> 5, s = tid & 31;
        float l[4];
        float mx = -3.4e38f;
        float tnb = thn[b];
#pragma unroll
        for (int j = 0; j < 4; ++j) {
            int k = s + 32 * j;
            l[j] = -0.5f * (tnb - 2.f * S_l[b][k] + munorm[k]);
            mx = fmaxf(mx, l[j]);
        }
#pragma unroll
        for (int msk = 1; msk < 32; msk <<= 1) mx = fmaxf(mx, __shfl_xor(mx, msk));
        float se = 0.f, ses = 0.f;
        float e[4];
#pragma unroll
        for (int j = 0; j < 4; ++j) {
            int k = s + 32 * j;
            e[j] = __expf(l[j] - mx);
            se += e[j];
            ses += e[j] * S_l[b][k];
        }
#pragma unroll
        for (int msk = 1; msk < 32; msk <<= 1) { se += __shfl_xor(se, msk); ses += __shfl_xor(ses, msk); }
        float inv = 1.f / se;
#pragma unroll
        for (int j = 0; j < 4; ++j) {
            int k = s + 32 * j;
            float wvv = e[j] * inv;
            w_l[b][k] = wvv;
            wbf[b][k] = (short)f2bf(wvv);
        }
        if (s == 0) SwS[b] = ses * inv;
    }
    __syncthreads();

    // ---- wGw pass: (w @ G) dotted back with w ----
    float lossA = 0.f;
    {
        floatx4 acc = {0.f, 0.f, 0.f, 0.f};
#pragma unroll
        for (int kc = 0; kc < 4; ++kc) {
            shortx8 a = *(const shortx8*)&wbf[m][kc * 32 + q * 8];
            acc = __builtin_amdgcn_mfma_f32_16x16x32_bf16(a, gfrag[kc], acc, 0, 0, 0);
        }
        float sg[4];
#pragma unroll
        for (int i = 0; i < 4; ++i) sg[i] = w_l[q * 4 + i][kcol] * acc[i];
#pragma unroll
        for (int msk = 1; msk < 16; msk <<= 1) {
#pragma unroll
            for (int i = 0; i < 4; ++i) sg[i] += __shfl_xor(sg[i], msk);
        }
        if (m == 0) {
#pragma unroll
            for (int i = 0; i < 4; ++i) part[wv][q * 4 + i][0] = sg[i];
        }
    }
    __syncthreads();
    if (tid < TB) {
        float wGw = 0.f;
#pragma unroll
        for (int w8 = 0; w8 < 8; ++w8) wGw += part[w8][tid][0];
        if (phalf == 0)
            lossA = 0.5f * temper * temper * (wGw - 2.f * SwS[tid] + thn[tid])
                    - temper * (float)Dn;           // the -tau*D trace constant, once per b
    }
    // no barrier needed: probe-0's part[] writes happen after the next barrier

    // ---- probe loop: 8 probes, register double-buffered staging ----
    float tracc = 0.f;
#pragma unroll
    for (int p = 0; p < 8; ++p) {
        if (p < 7) {  // issue next probe's loads first: in flight across compute
            const int4* g = (const int4*)(vrow + (size_t)(p0 + p + 1) * PB);
#pragma unroll
            for (int j = 0; j < 4; ++j) buf[(p + 1) & 1][j] = g[j];
        }
        // int 0/1 -> bf16 -1/+1, write to LDS
#pragma unroll
        for (int j = 0; j < 4; ++j) {
            int4 w4 = buf[p & 1][j];
            short4 h;
            h.x = (short)(0x3F80 | ((1 - w4.x) << 15));
            h.y = (short)(0x3F80 | ((1 - w4.y) << 15));
            h.z = (short)(0x3F80 | ((1 - w4.z) << 15));
            h.w = (short)(0x3F80 | ((1 - w4.w) << 15));
            *(short4*)&vt[r][c0 + j * 4] = h;
        }
        __syncthreads();
        floatx4 acc = {0.f, 0.f, 0.f, 0.f};
#pragma unroll
        for (int dc = 0; dc < 16; ++dc) {
            shortx8 a = *(const shortx8*)&vt[m][dc * 32 + q * 8];
            acc = __builtin_amdgcn_mfma_f32_16x16x32_bf16(a, mufrag[dc], acc, 0, 0, 0);
        }
        // epilogue: s1 = sum_k w*T^2, s2 = sum_k w*T  (per b-row)
        float s1[4], s2[4];
#pragma unroll
        for (int i = 0; i < 4; ++i) {
            float T = acc[i];
            float wt = w_l[q * 4 + i][kcol];
            s1[i] = wt * T * T;
            s2[i] = wt * T;
        }
#pragma unroll
        for (int msk = 1; msk < 16; msk <<= 1) {
#pragma unroll
            for (int i = 0; i < 4; ++i) {
                s1[i] += __shfl_xor(s1[i], msk);
                s2[i] += __shfl_xor(s2[i], msk);
            }
        }
        if (m == 0) {
#pragma unroll
            for (int i = 0; i < 4; ++i) {
                part[wv][q * 4 + i][0] = s1[i];
                part[wv][q * 4 + i][1] = s2[i];
            }
        }
        __syncthreads();
        if (tid < TB) {
            float S1 = 0.f, S2 = 0.f;
#pragma unroll
            for (int w8 = 0; w8 < 8; ++w8) { S1 += part[w8][tid][0]; S2 += part[w8][tid][1]; }
            tracc += S1 - S2 * S2;   // mubar.v == S2 identity: no extra contraction
        }
    }

    // ---- final per-block reduction ----
    if (tid < TB) {
        float res = temper * tracc * (1.0f / (float)Pn) + lossA;
#pragma unroll
        for (int msk = 1; msk < 16; msk <<= 1) res += __shfl_xor(res, msk);
        if (tid == 0) atomicAdd(out, res * (1.0f / (float)Bsz));
    }
}

extern "C" void kernel_launch(void* const* d_in, const int* in_sizes, int n_in,
                              void* d_out, int out_size, void* d_ws, size_t ws_size,
                              hipStream_t stream) {
    const float* thetas = (const float*)d_in[0];
    const float* alpha  = (const float*)d_in[1];
    const float* W      = (const float*)d_in[2];
    const int*   v_int  = (const int*)d_in[3];
    const int*   Np     = (const int*)d_in[4];
    // d_in[5] = K_alpha_samples: log K is a constant, drops out of grad/HVP.

    char* ws = (char*)d_ws;
    float*          mu_f   = (float*)ws;                              // 256 KB
    unsigned short* mu_bf  = (unsigned short*)(ws + 262144);          // 128 KB
    float*          munorm = (float*)(ws + 262144 + 131072);          // 512 B
    unsigned short* G_bf   = (unsigned short*)(ws + 262144 + 131072 + 1024); // 32 KB

    float* out = (float*)d_out;
    hipMemsetAsync(out, 0, sizeof(float), stream);
    k_mu  <<<dim3(Kn),  dim3(256), 0, stream>>>(alpha, W, mu_f, mu_bf, munorm);
    k_gram<<<dim3(Kn),  dim3(256), 0, stream>>>(mu_f, G_bf);
    k_main<<<dim3(512), dim3(512), 0, stream>>>(thetas, v_int, mu_bf, munorm, G_bf, Np, out);
}

// Round 2
// 217.899 us; speedup vs baseline: 1.0303x; 1.0303x over previous
//
#include <hip/hip_runtime.h>
#include <hip/hip_bf16.h>
#include <stdint.h>

#define Bsz 4096
#define Dn  512
#define Kn  128
#define Pn  16
#define An  32
#define TB  16

typedef __attribute__((ext_vector_type(4))) float  floatx4;
typedef __attribute__((ext_vector_type(8))) short  shortx8;

__device__ __forceinline__ unsigned short f2bf(float x) {
    union { float f; uint32_t u; } v; v.f = x;
    uint32_t u = v.u;
    uint32_t r = (u + 0x7FFFu + ((u >> 16) & 1u)) >> 16;
    return (unsigned short)r;
}

// ---------------- K1a: mu = alpha @ W (bf16 out) + ||mu_k||^2, also zeroes out ----------------
__global__ __launch_bounds__(256) void k_mu(const float* __restrict__ alpha,
                                            const float* __restrict__ W,
                                            unsigned short* __restrict__ mu_bf,
                                            float* __restrict__ munorm,
                                            float* __restrict__ out) {
    __shared__ float al[An];
    __shared__ float red[4];
    int k = blockIdx.x, t = threadIdx.x;
    if (k == 0 && t == 0) *out = 0.f;        // replaces the memset dispatch
    if (t < An) al[t] = alpha[k * An + t];
    __syncthreads();
    int d0 = t, d1 = t + 256;
    float a0 = 0.f, a1 = 0.f;
#pragma unroll
    for (int a = 0; a < An; ++a) {
        float av = al[a];
        a0 = fmaf(av, W[a * Dn + d0], a0);
        a1 = fmaf(av, W[a * Dn + d1], a1);
    }
    mu_bf[k * Dn + d0] = f2bf(a0);  mu_bf[k * Dn + d1] = f2bf(a1);
    float nrm = a0 * a0 + a1 * a1;
#pragma unroll
    for (int msk = 1; msk < 64; msk <<= 1) nrm += __shfl_xor(nrm, msk);
    if ((t & 63) == 0) red[t >> 6] = nrm;
    __syncthreads();
    if (t == 0) munorm[k] = red[0] + red[1] + red[2] + red[3];
}

// ---------------- K1b: Gram G = mu @ mu^T via MFMA (coalesced) ----------------
// grid 8 blocks x 512 thr; block = 16-row band of G; wave w = 16-col tile.
__global__ __launch_bounds__(512) void k_gram(const unsigned short* __restrict__ mu_bf,
                                              unsigned short* __restrict__ G_bf) {
    __shared__ short at[TB][520];
    const int tid = threadIdx.x;
    const int lane = tid & 63;
    const int wv = tid >> 6;
    const int m = lane & 15;
    const int q = lane >> 4;
    const int i0 = blockIdx.x * TB;

    // stage A rows (coalesced: 512 thr x 32 B cover 16 KB)
    const int r = tid >> 5, c0 = (tid & 31) * 16;
    const int4* src = (const int4*)(mu_bf + (size_t)(i0 + r) * Dn + c0);
    *(int4*)&at[r][c0]     = src[0];
    *(int4*)&at[r][c0 + 8] = src[1];

    // B frags: column kcol of G = row kcol of mu (symmetric), contiguous
    const int kcol = wv * 16 + m;
    shortx8 bfrag[16];
    const unsigned short* mb = mu_bf + (size_t)kcol * Dn + q * 8;
#pragma unroll
    for (int dc = 0; dc < 16; ++dc) bfrag[dc] = *(const shortx8*)(mb + dc * 32);
    __syncthreads();

    floatx4 acc = {0.f, 0.f, 0.f, 0.f};
#pragma unroll
    for (int dc = 0; dc < 16; ++dc) {
        shortx8 a = *(const shortx8*)&at[m][dc * 32 + q * 8];
        acc = __builtin_amdgcn_mfma_f32_16x16x32_bf16(a, bfrag[dc], acc, 0, 0, 0);
    }
#pragma unroll
    for (int i = 0; i < 4; ++i)
        G_bf[(size_t)(i0 + q * 4 + i) * Kn + kcol] = f2bf(acc[i]);
}

// ---------------- K3: fused S/softmax/wGw + streaming probe contraction ----------------
// 1 barrier per probe: LDS vt[2] + part[2] double-buffered; prefetch issued
// AFTER the barrier so __syncthreads' vmcnt(0) drain never kills the overlap.
__global__ __launch_bounds__(512, 4) void k_main(
    const float* __restrict__ thetas,
    const int* __restrict__ v_int,
    const unsigned short* __restrict__ mu_bf,
    const float* __restrict__ munorm,
    const unsigned short* __restrict__ G_bf,
    const int* __restrict__ Np,
    float* __restrict__ out)
{
    __shared__ short vt[2][TB][520];
    __shared__ float S_l[TB][132];
    __shared__ float w_l[TB][132];
    __shared__ short wbf[TB][136];
    __shared__ float part[2][8][TB][2];
    __shared__ float thn[TB];
    __shared__ float SwS[TB];

    const int tid = threadIdx.x;
    const int lane = tid & 63;
    const int wv = tid >> 6;
    const int m = lane & 15;
    const int q = lane >> 4;

    const int tileb = blockIdx.x >> 1;
    const int phalf = blockIdx.x & 1;
    const int b0 = tileb * TB;
    const int p0 = phalf * 8;

    const float Nf = (float)(*Np);
    const float temper = Nf / (Nf + 1.0f);

    const int kcol = wv * 16 + m;
    shortx8 mufrag[16];
    {
        const unsigned short* mb = mu_bf + (size_t)kcol * Dn + q * 8;
#pragma unroll
        for (int dc = 0; dc < 16; ++dc)
            mufrag[dc] = *(const shortx8*)(mb + dc * 32);
    }

    const int r = tid >> 5;
    const int c0 = (tid & 31) * 16;
    const size_t PB = (size_t)Bsz * Dn;
    const int* vrow = v_int + (size_t)(b0 + r) * Dn + c0;

    int4 buf[4];
    {   // prefetch probe p0 (lands during prologue; consumed at loop p=0)
        const int4* g = (const int4*)(vrow + (size_t)p0 * PB);
#pragma unroll
        for (int j = 0; j < 4; ++j) buf[j] = g[j];
    }
    {   // stage theta -> vt[0] (bf16), ||theta||^2 fp32
        const float4* tg = (const float4*)(thetas + (size_t)(b0 + r) * Dn + c0);
        float tn = 0.f;
#pragma unroll
        for (int j = 0; j < 4; ++j) {
            float4 f = tg[j];
            tn += f.x * f.x + f.y * f.y + f.z * f.z + f.w * f.w;
            short4 h;
            h.x = (short)f2bf(f.x); h.y = (short)f2bf(f.y);
            h.z = (short)f2bf(f.z); h.w = (short)f2bf(f.w);
            *(short4*)&vt[0][r][c0 + j * 4] = h;
        }
#pragma unroll
        for (int msk = 1; msk < 32; msk <<= 1) tn += __shfl_xor(tn, msk);
        if ((tid & 31) == 0) thn[r] = tn;
    }
    __syncthreads();

    // ---- S = theta @ mu^T ----
    {
        floatx4 acc = {0.f, 0.f, 0.f, 0.f};
#pragma unroll
        for (int dc = 0; dc < 16; ++dc) {
            shortx8 a = *(const shortx8*)&vt[0][m][dc * 32 + q * 8];
            acc = __builtin_amdgcn_mfma_f32_16x16x32_bf16(a, mufrag[dc], acc, 0, 0, 0);
        }
#pragma unroll
        for (int i = 0; i < 4; ++i) S_l[q * 4 + i][kcol] = acc[i];
    }
    __syncthreads();

    // ---- softmax over k (32 threads per b-row) ----
    {
        const int b = tid >> 5, s = tid & 31;
        float l[4];
        float mx = -3.4e38f;
        float tnb = thn[b];
#pragma unroll
        for (int j = 0; j < 4; ++j) {
            int k = s + 32 * j;
            l[j] = -0.5f * (tnb - 2.f * S_l[b][k] + munorm[k]);
            mx = fmaxf(mx, l[j]);
        }
#pragma unroll
        for (int msk = 1; msk < 32; msk <<= 1) mx = fmaxf(mx, __shfl_xor(mx, msk));
        float se = 0.f, ses = 0.f;
        float e[4];
#pragma unroll
        for (int j = 0; j < 4; ++j) {
            int k = s + 32 * j;
            e[j] = __expf(l[j] - mx);
            se += e[j];
            ses += e[j] * S_l[b][k];
        }
#pragma unroll
        for (int msk = 1; msk < 32; msk <<= 1) { se += __shfl_xor(se, msk); ses += __shfl_xor(ses, msk); }
        float inv = 1.f / se;
#pragma unroll
        for (int j = 0; j < 4; ++j) {
            int k = s + 32 * j;
            float wvv = e[j] * inv;
            w_l[b][k] = wvv;
            wbf[b][k] = (short)f2bf(wvv);
        }
        if (s == 0) SwS[b] = ses * inv;
    }
    __syncthreads();

    // ---- wGw: (w @ G) . w  (gfrag scoped: short live range, keeps VGPR<=128) ----
    {
        shortx8 gfrag[4];
        const unsigned short* gb = G_bf + (size_t)kcol * Kn + q * 8;
#pragma unroll
        for (int kc = 0; kc < 4; ++kc) gfrag[kc] = *(const shortx8*)(gb + kc * 32);
        floatx4 acc = {0.f, 0.f, 0.f, 0.f};
#pragma unroll
        for (int kc = 0; kc < 4; ++kc) {
            shortx8 a = *(const shortx8*)&wbf[m][kc * 32 + q * 8];
            acc = __builtin_amdgcn_mfma_f32_16x16x32_bf16(a, gfrag[kc], acc, 0, 0, 0);
        }
        float sg[4];
#pragma unroll
        for (int i = 0; i < 4; ++i) sg[i] = w_l[q * 4 + i][kcol] * acc[i];
#pragma unroll
        for (int msk = 1; msk < 16; msk <<= 1) {
#pragma unroll
            for (int i = 0; i < 4; ++i) sg[i] += __shfl_xor(sg[i], msk);
        }
        if (m == 0) {
#pragma unroll
            for (int i = 0; i < 4; ++i) part[0][wv][q * 4 + i][0] = sg[i];
        }
    }
    __syncthreads();

    float lossA = 0.f, tracc = 0.f;
    if (tid < TB) {
        float wGw = 0.f;
#pragma unroll
        for (int w8 = 0; w8 < 8; ++w8) wGw += part[0][w8][tid][0];
        if (phalf == 0)
            lossA = 0.5f * temper * temper * (wGw - 2.f * SwS[tid] + thn[tid])
                    - temper * (float)Dn;
    }
    // readers above finish before probe-0's part[0] writes (those follow barrier p=0)

    // ---- probe loop: 1 barrier per probe ----
#pragma unroll
    for (int p = 0; p < 8; ++p) {
        // convert current buf -> vt[p&1]  (safe: reads of this buffer from
        // probe p-2 completed before barrier p-1)
#pragma unroll
        for (int j = 0; j < 4; ++j) {
            int4 w4 = buf[j];
            short4 h;
            h.x = (short)(0x3F80 | ((w4.x ^ 1) << 15));
            h.y = (short)(0x3F80 | ((w4.y ^ 1) << 15));
            h.z = (short)(0x3F80 | ((w4.z ^ 1) << 15));
            h.w = (short)(0x3F80 | ((w4.w ^ 1) << 15));
            *(short4*)&vt[p & 1][r][c0 + j * 4] = h;
        }
        __syncthreads();
        // prefetch AFTER the barrier: never drained by syncthreads' vmcnt(0);
        // lands during MFMA phase, consumed at next iteration's convert
        if (p < 7) {
            const int4* g = (const int4*)(vrow + (size_t)(p0 + p + 1) * PB);
#pragma unroll
            for (int j = 0; j < 4; ++j) buf[j] = g[j];
        }
        if (p > 0 && tid < TB) {
            float S1 = 0.f, S2 = 0.f;
#pragma unroll
            for (int w8 = 0; w8 < 8; ++w8) {
                S1 += part[(p - 1) & 1][w8][tid][0];
                S2 += part[(p - 1) & 1][w8][tid][1];
            }
            tracc += S1 - S2 * S2;
        }
        floatx4 acc = {0.f, 0.f, 0.f, 0.f};
#pragma unroll
        for (int dc = 0; dc < 16; ++dc) {
            shortx8 a = *(const shortx8*)&vt[p & 1][m][dc * 32 + q * 8];
            acc = __builtin_amdgcn_mfma_f32_16x16x32_bf16(a, mufrag[dc], acc, 0, 0, 0);
        }
        float s1[4], s2[4];
#pragma unroll
        for (int i = 0; i < 4; ++i) {
            float T = acc[i];
            float wt = w_l[q * 4 + i][kcol];
            s1[i] = wt * T * T;
            s2[i] = wt * T;
        }
#pragma unroll
        for (int msk = 1; msk < 16; msk <<= 1) {
#pragma unroll
            for (int i = 0; i < 4; ++i) {
                s1[i] += __shfl_xor(s1[i], msk);
                s2[i] += __shfl_xor(s2[i], msk);
            }
        }
        if (m == 0) {
#pragma unroll
            for (int i = 0; i < 4; ++i) {
                part[p & 1][wv][q * 4 + i][0] = s1[i];
                part[p & 1][wv][q * 4 + i][1] = s2[i];
            }
        }
        // no trailing barrier: next iteration's barrier orders part/vt reuse
    }
    __syncthreads();
    if (tid < TB) {
        float S1 = 0.f, S2 = 0.f;
#pragma unroll
        for (int w8 = 0; w8 < 8; ++w8) {
            S1 += part[1][w8][tid][0];
            S2 += part[1][w8][tid][1];
        }
        tracc += S1 - S2 * S2;
        float res = temper * tracc * (1.0f / (float)Pn) + lossA;
#pragma unroll
        for (int msk = 1; msk < 16; msk <<= 1) res += __shfl_xor(res, msk);
        if (tid == 0) atomicAdd(out, res * (1.0f / (float)Bsz));
    }
}

extern "C" void kernel_launch(void* const* d_in, const int* in_sizes, int n_in,
                              void* d_out, int out_size, void* d_ws, size_t ws_size,
                              hipStream_t stream) {
    const float* thetas = (const float*)d_in[0];
    const float* alpha  = (const float*)d_in[1];
    const float* W      = (const float*)d_in[2];
    const int*   v_int  = (const int*)d_in[3];
    const int*   Np     = (const int*)d_in[4];

    char* ws = (char*)d_ws;
    unsigned short* mu_bf  = (unsigned short*)ws;                    // 128 KB
    float*          munorm = (float*)(ws + 131072);                  // 512 B
    unsigned short* G_bf   = (unsigned short*)(ws + 131072 + 1024);  // 32 KB

    float* out = (float*)d_out;
    k_mu  <<<dim3(Kn), dim3(256), 0, stream>>>(alpha, W, mu_bf, munorm, out);
    k_gram<<<dim3(8),  dim3(512), 0, stream>>>(mu_bf, G_bf);
    k_main<<<dim3(512), dim3(512), 0, stream>>>(thetas, v_int, mu_bf, munorm, G_bf, Np, out);
}